// Round 1
// baseline (317.514 us; speedup 1.0000x reference)
//
#include <hip/hip_runtime.h>
#include <hip/hip_bf16.h>
#include <cstdint>
#include <cstddef>

typedef __attribute__((ext_vector_type(8))) short s8v;   // 8 x bf16 bits (4 VGPRs)
typedef __attribute__((ext_vector_type(4))) float f4v;   // MFMA accumulator

#define MFMA_BF16(a, b, c) __builtin_amdgcn_mfma_f32_16x16x32_bf16((a), (b), (c), 0, 0, 0)

// round-to-nearest-even f32 -> bf16 bits (finite inputs)
__device__ __forceinline__ short f2bf(float f) {
    unsigned u = __builtin_bit_cast(unsigned, f);
    u += 0x7FFFu + ((u >> 16) & 1u);
    return (short)(u >> 16);
}

// async global->LDS, 16B per lane. lds dest must be wave-uniform base (+lane*16 by HW).
#define GLDS16(gsrc, ldst)                                                                   \
    __builtin_amdgcn_global_load_lds(                                                        \
        (const __attribute__((address_space(1))) unsigned int*)(gsrc),                       \
        (__attribute__((address_space(3))) unsigned int*)(ldst), 16, 0, 0)

// ---------------------------------------------------------------------------
// x fp32 -> bf16 (vectorized)
// ---------------------------------------------------------------------------
__global__ void convert_x(const float4* __restrict__ in, short4* __restrict__ out, int n4) {
    int i = blockIdx.x * blockDim.x + threadIdx.x;
    int stride = gridDim.x * blockDim.x;
    for (; i < n4; i += stride) {
        float4 v = in[i];
        short4 o;
        o.x = f2bf(v.x); o.y = f2bf(v.y); o.z = f2bf(v.z); o.w = f2bf(v.w);
        out[i] = o;
    }
}

// ---------------------------------------------------------------------------
// W[k][n] fp32 -> Wt[n][k] bf16   (1024x1024 each, z selects which weight)
// ---------------------------------------------------------------------------
__global__ void transpose_w(const float* __restrict__ a0, const float* __restrict__ a1,
                            const float* __restrict__ a2, const float* __restrict__ a3,
                            short* __restrict__ outb) {
    const float* src = (blockIdx.z == 0) ? a0 : (blockIdx.z == 1) ? a1 : (blockIdx.z == 2) ? a2 : a3;
    short* dst = outb + (size_t)blockIdx.z * 1048576;
    __shared__ float t[32][33];
    const int n0 = blockIdx.x * 32, k0 = blockIdx.y * 32;
    const int tid = threadIdx.x;
    const int rr = tid >> 3, c4 = (tid & 7) * 4;
    float4 v = *(const float4*)(src + (size_t)(k0 + rr) * 1024 + n0 + c4);
    t[rr][c4 + 0] = v.x; t[rr][c4 + 1] = v.y; t[rr][c4 + 2] = v.z; t[rr][c4 + 3] = v.w;
    __syncthreads();
    short4 o;
    o.x = f2bf(t[c4 + 0][rr]); o.y = f2bf(t[c4 + 1][rr]);
    o.z = f2bf(t[c4 + 2][rr]); o.w = f2bf(t[c4 + 3][rr]);
    *(short4*)(dst + (size_t)(n0 + rr) * 1024 + k0 + c4) = o;
}

// ---------------------------------------------------------------------------
// GEMM: C = op(A[M][K] @ B[N][K]^T + bias) * alpha    (A,B bf16 row-major, K%64==0)
// MODE 0: C[m][n] = (dot + bias[n]) * alpha          (OUT_T float or bf16)
// MODE 1: transposed store for V: logical row=n-dim(M here), col=x-row(N here):
//         C[(col>>11)*2048*1024 + row*2048 + (col&2047)] = dot + bias[row]   (bf16)
// 128x128 tile, BK=64, 4 waves, 4x4 16x16x32 MFMA per wave.
// LDS tiles XOR-swizzled (byte ^= (row&7)<<4) with pre-swizzled global source.
// ---------------------------------------------------------------------------
template <typename OUT_T, int MODE>
__global__ __launch_bounds__(256, 2) void gemm_bt(const short* __restrict__ A,
                                                  const short* __restrict__ B,
                                                  const float* __restrict__ bias,
                                                  OUT_T* __restrict__ C,
                                                  int M, int N, int K, float alpha) {
    __shared__ short As[128 * 64];
    __shared__ short Bs[128 * 64];
    const int tid = threadIdx.x;
    const int lane = tid & 63;
    const int w = tid >> 6;
    const int wr = w >> 1, wc = w & 1;
    const int m0 = blockIdx.y * 128, n0 = blockIdx.x * 128;
    const int KB = K * 2;  // row bytes

    f4v acc[4][4] = {};

    for (int kt = 0; kt < K; kt += 64) {
#pragma unroll
        for (int i = 0; i < 4; i++) {
            int o = tid * 16 + i * 4096;      // linear LDS byte offset
            int r = o >> 7;                   // tile row
            int cs = (o & 127) ^ ((r & 7) << 4);  // pre-swizzled source column byte
            GLDS16((const char*)A + (size_t)(m0 + r) * KB + kt * 2 + cs,
                   (char*)As + (w * 1024 + i * 4096));
            GLDS16((const char*)B + (size_t)(n0 + r) * KB + kt * 2 + cs,
                   (char*)Bs + (w * 1024 + i * 4096));
        }
        __syncthreads();
#pragma unroll
        for (int kk = 0; kk < 2; kk++) {
            s8v af[4], bf[4];
#pragma unroll
            for (int mi = 0; mi < 4; mi++) {
                int r = wr * 64 + mi * 16 + (lane & 15);
                int cb = (((lane >> 4) * 16) + kk * 64) ^ ((r & 7) << 4);
                af[mi] = *(const s8v*)((const char*)As + r * 128 + cb);
            }
#pragma unroll
            for (int ni = 0; ni < 4; ni++) {
                int r = wc * 64 + ni * 16 + (lane & 15);
                int cb = (((lane >> 4) * 16) + kk * 64) ^ ((r & 7) << 4);
                bf[ni] = *(const s8v*)((const char*)Bs + r * 128 + cb);
            }
#pragma unroll
            for (int mi = 0; mi < 4; mi++)
#pragma unroll
                for (int ni = 0; ni < 4; ni++)
                    acc[mi][ni] = MFMA_BF16(af[mi], bf[ni], acc[mi][ni]);
        }
        __syncthreads();
    }

    // epilogue: C/D layout col=lane&15, row=(lane>>4)*4+j
#pragma unroll
    for (int mi = 0; mi < 4; mi++) {
#pragma unroll
        for (int ni = 0; ni < 4; ni++) {
            int row = m0 + wr * 64 + mi * 16 + ((lane >> 4) << 2);
            int col = n0 + wc * 64 + ni * 16 + (lane & 15);
#pragma unroll
            for (int j = 0; j < 4; j++) {
                float v = acc[mi][ni][j];
                if constexpr (MODE == 0) {
                    v = (v + bias[col]) * alpha;
                    size_t idx = (size_t)(row + j) * N + col;
                    if constexpr (sizeof(OUT_T) == 2) C[idx] = (OUT_T)f2bf(v);
                    else C[idx] = v;
                } else {
                    v = (v + bias[row + j]) * alpha;
                    size_t idx = (size_t)(col >> 11) * (2048 * 1024) + (size_t)(row + j) * 2048 + (col & 2047);
                    C[idx] = (OUT_T)f2bf(v);
                }
            }
        }
    }
}

// ---------------------------------------------------------------------------
// Flash attention fwd (bf16 MFMA, fp32 online softmax).
// Q pre-scaled by 0.125*log2e in its GEMM epilogue, so P = exp2(S - m).
// Qb,Kb: [B*S][1024] bf16 (head at cols h*64..h*64+64)
// Vtb:   [(b*1024 + h*64 + d)][2048] bf16  (transposed V)
// AOb:   [B*S][1024] bf16
// Block: 4 waves, 128 q-rows (32 per wave), KBLK=64.
// ---------------------------------------------------------------------------
__global__ __launch_bounds__(256, 2) void attn_fwd(const short* __restrict__ Qb,
                                                   const short* __restrict__ Kb,
                                                   const short* __restrict__ Vtb,
                                                   short* __restrict__ AOb) {
    __shared__ short Ks[64 * 64];      // [s][d] swizzled
    __shared__ short Vs[64 * 64];      // [d][s] swizzled
    __shared__ short Ps[4][32 * 64];   // per-wave P tile, swizzled

    const int tid = threadIdx.x, lane = tid & 63, w = tid >> 6;
    const int qt = blockIdx.x;        // 0..15
    const int bh = blockIdx.y;        // 0..63
    const int b = bh >> 4, h = bh & 15;
    const int q0 = qt * 128 + w * 32; // within-batch q row base for this wave

    // Q fragments in registers: rows [q0, q0+32), k = head dim 64
    s8v qf[2][2];
#pragma unroll
    for (int fr = 0; fr < 2; fr++)
#pragma unroll
        for (int kk = 0; kk < 2; kk++) {
            int row = b * 2048 + q0 + fr * 16 + (lane & 15);
            qf[fr][kk] = *(const s8v*)(Qb + (size_t)row * 1024 + h * 64 + (lane >> 4) * 8 + kk * 32);
        }

    f4v oacc[2][4] = {};
    float m_[2][4], l_[2][4];
#pragma unroll
    for (int fr = 0; fr < 2; fr++)
#pragma unroll
        for (int j = 0; j < 4; j++) { m_[fr][j] = -1e30f; l_[fr][j] = 0.f; }

    for (int s0 = 0; s0 < 2048; s0 += 64) {
        // stage K tile [64 s][64 d] and Vt tile [64 d][64 s], both swizzled
#pragma unroll
        for (int i = 0; i < 2; i++) {
            int o = tid * 16 + i * 4096;
            int r = o >> 7;
            int cs = (o & 127) ^ ((r & 7) << 4);
            GLDS16((const char*)Kb + (size_t)(b * 2048 + s0 + r) * 2048 + h * 128 + cs,
                   (char*)Ks + (w * 1024 + i * 4096));
            GLDS16((const char*)Vtb + (size_t)(b * 1024 + h * 64 + r) * 4096 + s0 * 2 + cs,
                   (char*)Vs + (w * 1024 + i * 4096));
        }
        __syncthreads();

        // S = Q K^T  (fragments: fr = q row-block, fc = s col-block)
        f4v sf[2][4] = {};
#pragma unroll
        for (int kk = 0; kk < 2; kk++) {
            s8v kf[4];
#pragma unroll
            for (int fc = 0; fc < 4; fc++) {
                int r = fc * 16 + (lane & 15);
                int cb = (((lane >> 4) * 16) + kk * 64) ^ ((r & 7) << 4);
                kf[fc] = *(const s8v*)((const char*)Ks + r * 128 + cb);
            }
#pragma unroll
            for (int fr = 0; fr < 2; fr++)
#pragma unroll
                for (int fc = 0; fc < 4; fc++)
                    sf[fr][fc] = MFMA_BF16(qf[fr][kk], kf[fc], sf[fr][fc]);
        }

        // online softmax (rows split across regs j and 16-lane groups)
        float fac[2][4];
#pragma unroll
        for (int fr = 0; fr < 2; fr++)
#pragma unroll
            for (int j = 0; j < 4; j++) {
                float tm = fmaxf(fmaxf(sf[fr][0][j], sf[fr][1][j]), fmaxf(sf[fr][2][j], sf[fr][3][j]));
                tm = fmaxf(tm, __shfl_xor(tm, 1, 64));
                tm = fmaxf(tm, __shfl_xor(tm, 2, 64));
                tm = fmaxf(tm, __shfl_xor(tm, 4, 64));
                tm = fmaxf(tm, __shfl_xor(tm, 8, 64));
                float mn = fmaxf(m_[fr][j], tm);
                fac[fr][j] = __builtin_amdgcn_exp2f(m_[fr][j] - mn);
                m_[fr][j] = mn;
                l_[fr][j] *= fac[fr][j];
            }
#pragma unroll
        for (int fr = 0; fr < 2; fr++)
#pragma unroll
            for (int dv = 0; dv < 4; dv++)
#pragma unroll
                for (int j = 0; j < 4; j++) oacc[fr][dv][j] *= fac[fr][j];

        // P = exp2(S - m), write to per-wave LDS in swizzled [32][64] layout
        float rs[2][4] = {};
#pragma unroll
        for (int fr = 0; fr < 2; fr++)
#pragma unroll
            for (int fc = 0; fc < 4; fc++)
#pragma unroll
                for (int j = 0; j < 4; j++) {
                    float p = __builtin_amdgcn_exp2f(sf[fr][fc][j] - m_[fr][j]);
                    rs[fr][j] += p;
                    int row = fr * 16 + ((lane >> 4) << 2) + j;
                    int cb = ((fc * 16 + (lane & 15)) * 2) ^ ((row & 7) << 4);
                    *(short*)((char*)Ps[w] + row * 128 + cb) = f2bf(p);
                }
#pragma unroll
        for (int fr = 0; fr < 2; fr++)
#pragma unroll
            for (int j = 0; j < 4; j++) {
                float s = rs[fr][j];
                s += __shfl_xor(s, 1, 64);
                s += __shfl_xor(s, 2, 64);
                s += __shfl_xor(s, 4, 64);
                s += __shfl_xor(s, 8, 64);
                l_[fr][j] += s;
            }

        // O += P @ V
#pragma unroll
        for (int kk = 0; kk < 2; kk++) {
            s8v pf[2], vf[4];
#pragma unroll
            for (int fr = 0; fr < 2; fr++) {
                int r = fr * 16 + (lane & 15);
                int cb = (((lane >> 4) * 16) + kk * 64) ^ ((r & 7) << 4);
                pf[fr] = *(const s8v*)((const char*)Ps[w] + r * 128 + cb);
            }
#pragma unroll
            for (int dv = 0; dv < 4; dv++) {
                int r = dv * 16 + (lane & 15);
                int cb = (((lane >> 4) * 16) + kk * 64) ^ ((r & 7) << 4);
                vf[dv] = *(const s8v*)((const char*)Vs + r * 128 + cb);
            }
#pragma unroll
            for (int fr = 0; fr < 2; fr++)
#pragma unroll
                for (int dv = 0; dv < 4; dv++)
                    oacc[fr][dv] = MFMA_BF16(pf[fr], vf[dv], oacc[fr][dv]);
        }
        __syncthreads();
    }

    // normalize and store bf16
#pragma unroll
    for (int fr = 0; fr < 2; fr++)
#pragma unroll
        for (int dv = 0; dv < 4; dv++) {
            int row = q0 + fr * 16 + ((lane >> 4) << 2);
            int col = h * 64 + dv * 16 + (lane & 15);
#pragma unroll
            for (int j = 0; j < 4; j++) {
                float v = oacc[fr][dv][j] / l_[fr][j];
                AOb[(size_t)(b * 2048 + row + j) * 1024 + col] = f2bf(v);
            }
        }
}

// ---------------------------------------------------------------------------
extern "C" void kernel_launch(void* const* d_in, const int* in_sizes, int n_in,
                              void* d_out, int out_size, void* d_ws, size_t ws_size,
                              hipStream_t stream) {
    const float* x  = (const float*)d_in[0];
    const float* wq = (const float*)d_in[1];
    const float* bq = (const float*)d_in[2];
    const float* wk = (const float*)d_in[3];
    const float* bk = (const float*)d_in[4];
    const float* wv = (const float*)d_in[5];
    const float* bv = (const float*)d_in[6];
    const float* wo = (const float*)d_in[7];
    const float* bo = (const float*)d_in[8];
    float* out = (float*)d_out;

    char* ws = (char*)d_ws;
    const size_t MB16 = 16777216;  // 8192*1024*2
    short* xb  = (short*)(ws);              // x bf16 [8192][1024]
    short* qb  = (short*)(ws + 1 * MB16);   // Q bf16 (pre-scaled)
    short* kb  = (short*)(ws + 2 * MB16);   // K bf16
    short* vtb = (short*)(ws + 3 * MB16);   // V transposed bf16
    short* wT  = (short*)(ws + 4 * MB16);   // 4 x WT bf16 (wq,wk,wv,wo)
    short* aob = xb;                        // attention output reuses xb

    const float qscale = 0.125f * 1.4426950408889634f;  // 1/sqrt(64) * log2(e)

    convert_x<<<dim3(1024), dim3(256), 0, stream>>>((const float4*)x, (short4*)xb, 8388608 / 4);
    transpose_w<<<dim3(32, 32, 4), dim3(256), 0, stream>>>(wq, wk, wv, wo, wT);

    gemm_bt<short, 0><<<dim3(8, 64), dim3(256), 0, stream>>>(xb, wT, bq, qb, 8192, 1024, 1024, qscale);
    gemm_bt<short, 0><<<dim3(8, 64), dim3(256), 0, stream>>>(xb, wT + 1048576, bk, kb, 8192, 1024, 1024, 1.0f);
    gemm_bt<short, 1><<<dim3(64, 8), dim3(256), 0, stream>>>(wT + 2 * 1048576, xb, bv, vtb, 1024, 8192, 1024, 1.0f);

    attn_fwd<<<dim3(16, 64), dim3(256), 0, stream>>>(qb, kb, vtb, aob);

    gemm_bt<float, 0><<<dim3(8, 64), dim3(256), 0, stream>>>(aob, wT + 3 * 1048576, bo, out, 8192, 1024, 1024, 1.0f);
}

// Round 2
// 235.361 us; speedup vs baseline: 1.3491x; 1.3491x over previous
//
#include <hip/hip_runtime.h>
#include <hip/hip_bf16.h>
#include <cstdint>
#include <cstddef>

typedef __attribute__((ext_vector_type(8))) short s8v;   // 8 x bf16 bits (4 VGPRs)
typedef __attribute__((ext_vector_type(4))) float f4v;   // MFMA accumulator

#define MFMA_BF16(a, b, c) __builtin_amdgcn_mfma_f32_16x16x32_bf16((a), (b), (c), 0, 0, 0)

// round-to-nearest-even f32 -> bf16 bits (finite inputs)
__device__ __forceinline__ short f2bf(float f) {
    unsigned u = __builtin_bit_cast(unsigned, f);
    u += 0x7FFFu + ((u >> 16) & 1u);
    return (short)(u >> 16);
}

// packed f32 pair -> 2 x bf16 in one dword (lo = a, hi = b)
__device__ __forceinline__ unsigned cvt_pk_bf16(float a, float b) {
    unsigned r;
    asm("v_cvt_pk_bf16_f32 %0, %1, %2" : "=v"(r) : "v"(a), "v"(b));
    return r;
}

// async global->LDS, 16B per lane. lds dest must be wave-uniform base (+lane*16 by HW).
#define GLDS16(gsrc, ldst)                                                                   \
    __builtin_amdgcn_global_load_lds(                                                        \
        (const __attribute__((address_space(1))) unsigned int*)(gsrc),                       \
        (__attribute__((address_space(3))) unsigned int*)(ldst), 16, 0, 0)

// ---------------------------------------------------------------------------
// x fp32 -> bf16 (vectorized)
// ---------------------------------------------------------------------------
__global__ void convert_x(const float4* __restrict__ in, short4* __restrict__ out, int n4) {
    int i = blockIdx.x * blockDim.x + threadIdx.x;
    int stride = gridDim.x * blockDim.x;
    for (; i < n4; i += stride) {
        float4 v = in[i];
        short4 o;
        o.x = f2bf(v.x); o.y = f2bf(v.y); o.z = f2bf(v.z); o.w = f2bf(v.w);
        out[i] = o;
    }
}

// ---------------------------------------------------------------------------
// W[k][n] fp32 -> Wt[n][k] bf16   (1024x1024 each, z selects which weight)
// ---------------------------------------------------------------------------
__global__ void transpose_w(const float* __restrict__ a0, const float* __restrict__ a1,
                            const float* __restrict__ a2, const float* __restrict__ a3,
                            short* __restrict__ outb) {
    const float* src = (blockIdx.z == 0) ? a0 : (blockIdx.z == 1) ? a1 : (blockIdx.z == 2) ? a2 : a3;
    short* dst = outb + (size_t)blockIdx.z * 1048576;
    __shared__ float t[32][33];
    const int n0 = blockIdx.x * 32, k0 = blockIdx.y * 32;
    const int tid = threadIdx.x;
    const int rr = tid >> 3, c4 = (tid & 7) * 4;
    float4 v = *(const float4*)(src + (size_t)(k0 + rr) * 1024 + n0 + c4);
    t[rr][c4 + 0] = v.x; t[rr][c4 + 1] = v.y; t[rr][c4 + 2] = v.z; t[rr][c4 + 3] = v.w;
    __syncthreads();
    short4 o;
    o.x = f2bf(t[c4 + 0][rr]); o.y = f2bf(t[c4 + 1][rr]);
    o.z = f2bf(t[c4 + 2][rr]); o.w = f2bf(t[c4 + 3][rr]);
    *(short4*)(dst + (size_t)(n0 + rr) * 1024 + k0 + c4) = o;
}

// ---------------------------------------------------------------------------
// GEMM: C = op(A[M][K] @ B[N][K]^T + bias) * alpha    (A,B bf16 row-major, K%64==0)
// MODE 0: C[m][n] = (dot + bias[n]) * alpha          (OUT_T float or bf16)
// MODE 1: transposed store for V (row=n-dim, col=x-row), bf16.
// 128x128 tile, BK=64, 4 waves, 4x4 16x16x32 MFMA per wave.
// ---------------------------------------------------------------------------
template <typename OUT_T, int MODE>
__global__ __launch_bounds__(256, 2) void gemm_bt(const short* __restrict__ A,
                                                  const short* __restrict__ B,
                                                  const float* __restrict__ bias,
                                                  OUT_T* __restrict__ C,
                                                  int M, int N, int K, float alpha) {
    __shared__ short As[128 * 64];
    __shared__ short Bs[128 * 64];
    const int tid = threadIdx.x;
    const int lane = tid & 63;
    const int w = tid >> 6;
    const int wr = w >> 1, wc = w & 1;
    const int m0 = blockIdx.y * 128, n0 = blockIdx.x * 128;
    const int KB = K * 2;  // row bytes

    f4v acc[4][4] = {};

    for (int kt = 0; kt < K; kt += 64) {
#pragma unroll
        for (int i = 0; i < 4; i++) {
            int o = tid * 16 + i * 4096;      // linear LDS byte offset
            int r = o >> 7;                   // tile row
            int cs = (o & 127) ^ ((r & 7) << 4);  // pre-swizzled source column byte
            GLDS16((const char*)A + (size_t)(m0 + r) * KB + kt * 2 + cs,
                   (char*)As + (w * 1024 + i * 4096));
            GLDS16((const char*)B + (size_t)(n0 + r) * KB + kt * 2 + cs,
                   (char*)Bs + (w * 1024 + i * 4096));
        }
        __syncthreads();
#pragma unroll
        for (int kk = 0; kk < 2; kk++) {
            s8v af[4], bf[4];
#pragma unroll
            for (int mi = 0; mi < 4; mi++) {
                int r = wr * 64 + mi * 16 + (lane & 15);
                int cb = (((lane >> 4) * 16) + kk * 64) ^ ((r & 7) << 4);
                af[mi] = *(const s8v*)((const char*)As + r * 128 + cb);
            }
#pragma unroll
            for (int ni = 0; ni < 4; ni++) {
                int r = wc * 64 + ni * 16 + (lane & 15);
                int cb = (((lane >> 4) * 16) + kk * 64) ^ ((r & 7) << 4);
                bf[ni] = *(const s8v*)((const char*)Bs + r * 128 + cb);
            }
#pragma unroll
            for (int mi = 0; mi < 4; mi++)
#pragma unroll
                for (int ni = 0; ni < 4; ni++)
                    acc[mi][ni] = MFMA_BF16(af[mi], bf[ni], acc[mi][ni]);
        }
        __syncthreads();
    }

    // epilogue: C/D layout col=lane&15, row=(lane>>4)*4+j
#pragma unroll
    for (int mi = 0; mi < 4; mi++) {
#pragma unroll
        for (int ni = 0; ni < 4; ni++) {
            int row = m0 + wr * 64 + mi * 16 + ((lane >> 4) << 2);
            int col = n0 + wc * 64 + ni * 16 + (lane & 15);
#pragma unroll
            for (int j = 0; j < 4; j++) {
                float v = acc[mi][ni][j];
                if constexpr (MODE == 0) {
                    v = (v + bias[col]) * alpha;
                    size_t idx = (size_t)(row + j) * N + col;
                    if constexpr (sizeof(OUT_T) == 2) C[idx] = (OUT_T)f2bf(v);
                    else C[idx] = v;
                } else {
                    v = (v + bias[row + j]) * alpha;
                    size_t idx = (size_t)(col >> 11) * (2048 * 1024) + (size_t)(row + j) * 2048 + (col & 2047);
                    C[idx] = (OUT_T)f2bf(v);
                }
            }
        }
    }
}

// ---------------------------------------------------------------------------
// Flash attention fwd v2: swapped-operand MFMA, lane-local softmax state,
// packed-b64 P spill, double-buffered K/V with 2-phase prefetch.
// Q pre-scaled by 0.125*log2e in its GEMM epilogue, so P = exp2(S - m).
// Qb,Kb: [B*S][1024] bf16 (head at cols h*64..)   Vtb: [(b*1024+h*64+d)][2048] bf16
// AOb:   [B*S][1024] bf16
// 4 waves/block, 32 q-rows/wave, KVBLK=64, 32 k-tiles.
// ---------------------------------------------------------------------------
__global__ __launch_bounds__(256, 3) void attn_fwd(const short* __restrict__ Qb,
                                                   const short* __restrict__ Kb,
                                                   const short* __restrict__ Vtb,
                                                   short* __restrict__ AOb) {
    __shared__ short Ks[2][64 * 64];   // [s][d] swizzled, double buffered
    __shared__ short Vs[2][64 * 64];   // [d][s] swizzled, double buffered
    __shared__ short Ps[4][32 * 64];   // per-wave P tile [q][k], swizzled

    const int tid = threadIdx.x, lane = tid & 63, w = tid >> 6;
    const int lo = lane & 15, hi = lane >> 4;
    const int qt = blockIdx.x;        // 0..15
    const int bh = blockIdx.y;        // 0..63
    const int b = bh >> 4, h = bh & 15;
    const int q0 = qt * 128 + w * 32; // within-batch q row base for this wave

    // Q fragments (B-operand: col = q = lo), rows [q0, q0+32)
    s8v qf[2][2];
#pragma unroll
    for (int fr = 0; fr < 2; fr++)
#pragma unroll
        for (int kk = 0; kk < 2; kk++) {
            int row = b * 2048 + q0 + fr * 16 + lo;
            qf[fr][kk] = *(const s8v*)(Qb + (size_t)row * 1024 + h * 64 + hi * 8 + kk * 32);
        }

    f4v oaccT[2][4] = {};              // O^T: col=q=lo, row=d within dv-block
    float m_[2] = {-1e30f, -1e30f};
    float l_[2] = {0.f, 0.f};

    auto STAGE = [&](int s0, int bi) {
#pragma unroll
        for (int i = 0; i < 2; i++) {
            int o = tid * 16 + i * 4096;
            int r = o >> 7;
            int cs = (o & 127) ^ ((r & 7) << 4);
            GLDS16((const char*)Kb + (size_t)(b * 2048 + s0 + r) * 2048 + h * 128 + cs,
                   (char*)Ks[bi] + w * 1024 + i * 4096);
            GLDS16((const char*)Vtb + (size_t)(b * 1024 + h * 64 + r) * 4096 + (size_t)s0 * 2 + cs,
                   (char*)Vs[bi] + w * 1024 + i * 4096);
        }
    };

    STAGE(0, 0);
    __syncthreads();

    int cur = 0;
    for (int t = 0; t < 32; t++) {
        // prefetch next tile into the other buffer (overlaps with compute below)
        if (t < 31) STAGE((t + 1) * 64, cur ^ 1);

        // S^T = K Q^T : sf[fr][fc]: col=q=lo, row k = fc*16 + hi*4 + j
        f4v sf[2][4] = {};
#pragma unroll
        for (int kk = 0; kk < 2; kk++) {
            s8v kf[4];
#pragma unroll
            for (int fc = 0; fc < 4; fc++) {
                int r = fc * 16 + lo;
                int cb = (hi * 16 + kk * 64) ^ ((r & 7) << 4);
                kf[fc] = *(const s8v*)((const char*)Ks[cur] + r * 128 + cb);
            }
#pragma unroll
            for (int fr = 0; fr < 2; fr++)
#pragma unroll
                for (int fc = 0; fc < 4; fc++)
                    sf[fr][fc] = MFMA_BF16(kf[fc], qf[fr][kk], sf[fr][fc]);
        }

        // lane-local online softmax (each lane owns q = fr*16 + lo; 16 k-vals in regs)
#pragma unroll
        for (int fr = 0; fr < 2; fr++) {
            float t0 = fmaxf(fmaxf(sf[fr][0][0], sf[fr][0][1]), fmaxf(sf[fr][0][2], sf[fr][0][3]));
            float t1 = fmaxf(fmaxf(sf[fr][1][0], sf[fr][1][1]), fmaxf(sf[fr][1][2], sf[fr][1][3]));
            float t2 = fmaxf(fmaxf(sf[fr][2][0], sf[fr][2][1]), fmaxf(sf[fr][2][2], sf[fr][2][3]));
            float t3 = fmaxf(fmaxf(sf[fr][3][0], sf[fr][3][1]), fmaxf(sf[fr][3][2], sf[fr][3][3]));
            float tm = fmaxf(fmaxf(t0, t1), fmaxf(t2, t3));
            tm = fmaxf(tm, __shfl_xor(tm, 16, 64));
            tm = fmaxf(tm, __shfl_xor(tm, 32, 64));
            float mn = fmaxf(m_[fr], tm);
            float fac = __builtin_amdgcn_exp2f(m_[fr] - mn);
            m_[fr] = mn;
            float rs = 0.f;
            int q = fr * 16 + lo;
#pragma unroll
            for (int fc = 0; fc < 4; fc++) {
                float p0 = __builtin_amdgcn_exp2f(sf[fr][fc][0] - mn);
                float p1 = __builtin_amdgcn_exp2f(sf[fr][fc][1] - mn);
                float p2 = __builtin_amdgcn_exp2f(sf[fr][fc][2] - mn);
                float p3 = __builtin_amdgcn_exp2f(sf[fr][fc][3] - mn);
                rs += (p0 + p1) + (p2 + p3);
                unsigned pk01 = cvt_pk_bf16(p0, p1);
                unsigned pk23 = cvt_pk_bf16(p2, p3);
                int byte = (q * 128 + fc * 32 + hi * 8) ^ ((q & 7) << 4);
                *(unsigned long long*)((char*)Ps[w] + byte) =
                    ((unsigned long long)pk23 << 32) | pk01;
            }
            rs += __shfl_xor(rs, 16, 64);
            rs += __shfl_xor(rs, 32, 64);
            l_[fr] = l_[fr] * fac + rs;
#pragma unroll
            for (int dv = 0; dv < 4; dv++)
#pragma unroll
                for (int j = 0; j < 4; j++) oaccT[fr][dv][j] *= fac;
        }

        // O^T += V^T P^T : mfma(vf, pf); oaccT col=q=lo, row=d
#pragma unroll
        for (int kk = 0; kk < 2; kk++) {
            s8v vf[4], pf[2];
#pragma unroll
            for (int fr = 0; fr < 2; fr++) {
                int q = fr * 16 + lo;
                int cb = (kk * 64 + hi * 16) ^ ((q & 7) << 4);
                pf[fr] = *(const s8v*)((const char*)Ps[w] + q * 128 + cb);
            }
#pragma unroll
            for (int dv = 0; dv < 4; dv++) {
                int r = dv * 16 + lo;
                int cb = (kk * 64 + hi * 16) ^ ((r & 7) << 4);
                vf[dv] = *(const s8v*)((const char*)Vs[cur] + r * 128 + cb);
            }
#pragma unroll
            for (int fr = 0; fr < 2; fr++)
#pragma unroll
                for (int dv = 0; dv < 4; dv++)
                    oaccT[fr][dv] = MFMA_BF16(vf[dv], pf[fr], oaccT[fr][dv]);
        }
        __syncthreads();   // drains prefetch (vmcnt) + guards buffer swap
        cur ^= 1;
    }

    // normalize and store bf16 (O^T layout: q lane-local, d = dv*16 + hi*4 + j)
#pragma unroll
    for (int fr = 0; fr < 2; fr++) {
        float rl = 1.0f / l_[fr];
        size_t qrow = (size_t)(b * 2048 + q0 + fr * 16 + lo);
#pragma unroll
        for (int dv = 0; dv < 4; dv++) {
            short4 o;
            o.x = f2bf(oaccT[fr][dv][0] * rl);
            o.y = f2bf(oaccT[fr][dv][1] * rl);
            o.z = f2bf(oaccT[fr][dv][2] * rl);
            o.w = f2bf(oaccT[fr][dv][3] * rl);
            *(short4*)(AOb + qrow * 1024 + h * 64 + dv * 16 + hi * 4) = o;
        }
    }
}

// ---------------------------------------------------------------------------
extern "C" void kernel_launch(void* const* d_in, const int* in_sizes, int n_in,
                              void* d_out, int out_size, void* d_ws, size_t ws_size,
                              hipStream_t stream) {
    const float* x  = (const float*)d_in[0];
    const float* wq = (const float*)d_in[1];
    const float* bq = (const float*)d_in[2];
    const float* wk = (const float*)d_in[3];
    const float* bk = (const float*)d_in[4];
    const float* wv = (const float*)d_in[5];
    const float* bv = (const float*)d_in[6];
    const float* wo = (const float*)d_in[7];
    const float* bo = (const float*)d_in[8];
    float* out = (float*)d_out;

    char* ws = (char*)d_ws;
    const size_t MB16 = 16777216;  // 8192*1024*2
    short* xb  = (short*)(ws);              // x bf16 [8192][1024]
    short* qb  = (short*)(ws + 1 * MB16);   // Q bf16 (pre-scaled)
    short* kb  = (short*)(ws + 2 * MB16);   // K bf16
    short* vtb = (short*)(ws + 3 * MB16);   // V transposed bf16
    short* wT  = (short*)(ws + 4 * MB16);   // 4 x WT bf16 (wq,wk,wv,wo)
    short* aob = xb;                        // attention output reuses xb

    const float qscale = 0.125f * 1.4426950408889634f;  // 1/sqrt(64) * log2(e)

    convert_x<<<dim3(1024), dim3(256), 0, stream>>>((const float4*)x, (short4*)xb, 8388608 / 4);
    transpose_w<<<dim3(32, 32, 4), dim3(256), 0, stream>>>(wq, wk, wv, wo, wT);

    gemm_bt<short, 0><<<dim3(8, 64), dim3(256), 0, stream>>>(xb, wT, bq, qb, 8192, 1024, 1024, qscale);
    gemm_bt<short, 0><<<dim3(8, 64), dim3(256), 0, stream>>>(xb, wT + 1048576, bk, kb, 8192, 1024, 1024, 1.0f);
    gemm_bt<short, 1><<<dim3(64, 8), dim3(256), 0, stream>>>(wT + 2 * 1048576, xb, bv, vtb, 1024, 8192, 1024, 1.0f);

    attn_fwd<<<dim3(16, 64), dim3(256), 0, stream>>>(qb, kb, vtb, aob);

    gemm_bt<float, 0><<<dim3(8, 64), dim3(256), 0, stream>>>(aob, wT + 3 * 1048576, bo, out, 8192, 1024, 1024, 1.0f);
}

// Round 4
// 211.799 us; speedup vs baseline: 1.4991x; 1.1112x over previous
//
#include <hip/hip_runtime.h>
#include <hip/hip_bf16.h>
#include <cstdint>
#include <cstddef>

typedef __attribute__((ext_vector_type(8))) short s8v;    // 8 x bf16 bits (4 VGPRs)
typedef __attribute__((ext_vector_type(4))) float f4v;    // 16x16 MFMA accumulator
typedef __attribute__((ext_vector_type(16))) float f16v;  // 32x32 MFMA accumulator
typedef __attribute__((ext_vector_type(4))) unsigned u4v;

#define MFMA_BF16(a, b, c) __builtin_amdgcn_mfma_f32_16x16x32_bf16((a), (b), (c), 0, 0, 0)
#define MFMA32(a, b, c) __builtin_amdgcn_mfma_f32_32x32x16_bf16((a), (b), (c), 0, 0, 0)

// round-to-nearest-even f32 -> bf16 bits (finite inputs)
__device__ __forceinline__ short f2bf(float f) {
    unsigned u = __builtin_bit_cast(unsigned, f);
    u += 0x7FFFu + ((u >> 16) & 1u);
    return (short)(u >> 16);
}

// packed f32 pair -> 2 x bf16 in one dword (lo = a, hi = b)
__device__ __forceinline__ unsigned cvt_pk_bf16(float a, float b) {
    unsigned r;
    asm("v_cvt_pk_bf16_f32 %0, %1, %2" : "=v"(r) : "v"(a), "v"(b));
    return r;
}

// async global->LDS, 16B per lane. lds dest must be wave-uniform base (+lane*16 by HW).
#define GLDS16(gsrc, ldst)                                                                   \
    __builtin_amdgcn_global_load_lds(                                                        \
        (const __attribute__((address_space(1))) unsigned int*)(gsrc),                       \
        (__attribute__((address_space(3))) unsigned int*)(ldst), 16, 0, 0)

// ---------------------------------------------------------------------------
// x fp32 -> bf16 (vectorized)
// ---------------------------------------------------------------------------
__global__ void convert_x(const float4* __restrict__ in, short4* __restrict__ out, int n4) {
    int i = blockIdx.x * blockDim.x + threadIdx.x;
    int stride = gridDim.x * blockDim.x;
    for (; i < n4; i += stride) {
        float4 v = in[i];
        short4 o;
        o.x = f2bf(v.x); o.y = f2bf(v.y); o.z = f2bf(v.z); o.w = f2bf(v.w);
        out[i] = o;
    }
}

// ---------------------------------------------------------------------------
// W[k][n] fp32 -> Wt[n][k] bf16   (1024x1024 each, z selects which weight)
// ---------------------------------------------------------------------------
__global__ void transpose_w(const float* __restrict__ a0, const float* __restrict__ a1,
                            const float* __restrict__ a2, const float* __restrict__ a3,
                            short* __restrict__ outb) {
    const float* src = (blockIdx.z == 0) ? a0 : (blockIdx.z == 1) ? a1 : (blockIdx.z == 2) ? a2 : a3;
    short* dst = outb + (size_t)blockIdx.z * 1048576;
    __shared__ float t[32][33];
    const int n0 = blockIdx.x * 32, k0 = blockIdx.y * 32;
    const int tid = threadIdx.x;
    const int rr = tid >> 3, c4 = (tid & 7) * 4;
    float4 v = *(const float4*)(src + (size_t)(k0 + rr) * 1024 + n0 + c4);
    t[rr][c4 + 0] = v.x; t[rr][c4 + 1] = v.y; t[rr][c4 + 2] = v.z; t[rr][c4 + 3] = v.w;
    __syncthreads();
    short4 o;
    o.x = f2bf(t[c4 + 0][rr]); o.y = f2bf(t[c4 + 1][rr]);
    o.z = f2bf(t[c4 + 2][rr]); o.w = f2bf(t[c4 + 3][rr]);
    *(short4*)(dst + (size_t)(n0 + rr) * 1024 + k0 + c4) = o;
}

// ---------------------------------------------------------------------------
// GEMM: C = op(A[M][K] @ B[N][K]^T + bias) * alpha    (A,B bf16 row-major, K%64==0)
// MODE 0: C[m][n] = (dot + bias[n]) * alpha          (OUT_T float or bf16)
// MODE 1: transposed store for V (row=n-dim, col=x-row), bf16.
// 128x128 tile, BK=64, 4 waves, 4x4 16x16x32 MFMA per wave.
// ---------------------------------------------------------------------------
template <typename OUT_T, int MODE>
__global__ __launch_bounds__(256, 2) void gemm_bt(const short* __restrict__ A,
                                                  const short* __restrict__ B,
                                                  const float* __restrict__ bias,
                                                  OUT_T* __restrict__ C,
                                                  int M, int N, int K, float alpha) {
    __shared__ short As[128 * 64];
    __shared__ short Bs[128 * 64];
    const int tid = threadIdx.x;
    const int lane = tid & 63;
    const int w = tid >> 6;
    const int wr = w >> 1, wc = w & 1;
    const int m0 = blockIdx.y * 128, n0 = blockIdx.x * 128;
    const int KB = K * 2;  // row bytes

    f4v acc[4][4] = {};

    for (int kt = 0; kt < K; kt += 64) {
#pragma unroll
        for (int i = 0; i < 4; i++) {
            int o = tid * 16 + i * 4096;      // linear LDS byte offset
            int r = o >> 7;                   // tile row
            int cs = (o & 127) ^ ((r & 7) << 4);  // pre-swizzled source column byte
            GLDS16((const char*)A + (size_t)(m0 + r) * KB + kt * 2 + cs,
                   (char*)As + (w * 1024 + i * 4096));
            GLDS16((const char*)B + (size_t)(n0 + r) * KB + kt * 2 + cs,
                   (char*)Bs + (w * 1024 + i * 4096));
        }
        __syncthreads();
#pragma unroll
        for (int kk = 0; kk < 2; kk++) {
            s8v af[4], bf[4];
#pragma unroll
            for (int mi = 0; mi < 4; mi++) {
                int r = wr * 64 + mi * 16 + (lane & 15);
                int cb = (((lane >> 4) * 16) + kk * 64) ^ ((r & 7) << 4);
                af[mi] = *(const s8v*)((const char*)As + r * 128 + cb);
            }
#pragma unroll
            for (int ni = 0; ni < 4; ni++) {
                int r = wc * 64 + ni * 16 + (lane & 15);
                int cb = (((lane >> 4) * 16) + kk * 64) ^ ((r & 7) << 4);
                bf[ni] = *(const s8v*)((const char*)Bs + r * 128 + cb);
            }
#pragma unroll
            for (int mi = 0; mi < 4; mi++)
#pragma unroll
                for (int ni = 0; ni < 4; ni++)
                    acc[mi][ni] = MFMA_BF16(af[mi], bf[ni], acc[mi][ni]);
        }
        __syncthreads();
    }

    // epilogue: C/D layout col=lane&15, row=(lane>>4)*4+j
#pragma unroll
    for (int mi = 0; mi < 4; mi++) {
#pragma unroll
        for (int ni = 0; ni < 4; ni++) {
            int row = m0 + wr * 64 + mi * 16 + ((lane >> 4) << 2);
            int col = n0 + wc * 64 + ni * 16 + (lane & 15);
#pragma unroll
            for (int j = 0; j < 4; j++) {
                float v = acc[mi][ni][j];
                if constexpr (MODE == 0) {
                    v = (v + bias[col]) * alpha;
                    size_t idx = (size_t)(row + j) * N + col;
                    if constexpr (sizeof(OUT_T) == 2) C[idx] = (OUT_T)f2bf(v);
                    else C[idx] = v;
                } else {
                    v = (v + bias[row + j]) * alpha;
                    size_t idx = (size_t)(col >> 11) * (2048 * 1024) + (size_t)(row + j) * 2048 + (col & 2047);
                    C[idx] = (OUT_T)f2bf(v);
                }
            }
        }
    }
}

// ---------------------------------------------------------------------------
// Flash attention fwd v3: 32x32x16 MFMA, in-register P via cvt_pk + permlane32_swap
// (no P LDS round-trip), lane-local softmax (q = lane&31), defer-max (T13),
// double-buffered K/V with prefetch, setprio around MFMA clusters (T5).
// Q pre-scaled by 0.125*log2e in its GEMM epilogue, so P = exp2(S - m).
// Qb,Kb: [B*S][1024] bf16 (head at cols h*64..)   Vtb: [(b*1024+h*64+d)][2048] bf16
// AOb:   [B*S][1024] bf16
// 4 waves/block, 32 q-rows/wave (128/block), KVBLK=64, 32 k-tiles.
// S^T = K Q^T per 32x32 tile: lane owns q=lane&31, k = 8*(reg>>2)+4*H+(reg&3).
// PV B-frag (k = 16s+8H+{0..7}) built by 4 cvt_pk + 2 permlane32_swap per k-step.
// ---------------------------------------------------------------------------
__global__ __launch_bounds__(256, 4) void attn_fwd(const short* __restrict__ Qb,
                                                   const short* __restrict__ Kb,
                                                   const short* __restrict__ Vtb,
                                                   short* __restrict__ AOb) {
    __shared__ short Ks[2][64 * 64];   // [s][d] swizzled, double buffered
    __shared__ short Vs[2][64 * 64];   // [d][s] swizzled, double buffered

    const int tid = threadIdx.x, lane = tid & 63, w = tid >> 6;
    const int l5 = lane & 31, H = lane >> 5;
    const int qt = blockIdx.x;        // 0..15
    const int bh = blockIdx.y;        // 0..63
    const int b = bh >> 4, h = bh & 15;
    const int q0 = qt * 128 + w * 32; // within-batch q row base for this wave

    // Q fragments (B-operand: col q=l5, d = st*16 + H*8 + 0..7)
    s8v qf[4];
#pragma unroll
    for (int st = 0; st < 4; st++)
        qf[st] = *(const s8v*)(Qb + (size_t)(b * 2048 + q0 + l5) * 1024 + h * 64 + st * 16 + H * 8);

    f16v oacc[2] = {};                 // O^T: col q=l5, row d = dt*32+8*(r>>2)+4H+(r&3)
    float m_ = -1e30f, l_ = 0.f;

    auto STAGE = [&](int s0, int bi) {
#pragma unroll
        for (int i = 0; i < 2; i++) {
            int o = tid * 16 + i * 4096;
            int r = o >> 7;
            int cs = (o & 127) ^ ((r & 7) << 4);
            GLDS16((const char*)Kb + (size_t)(b * 2048 + s0 + r) * 2048 + h * 128 + cs,
                   (char*)Ks[bi] + w * 1024 + i * 4096);
            GLDS16((const char*)Vtb + (size_t)(b * 1024 + h * 64 + r) * 4096 + (size_t)s0 * 2 + cs,
                   (char*)Vs[bi] + w * 1024 + i * 4096);
        }
    };

    STAGE(0, 0);
    __syncthreads();

    int cur = 0;
    for (int t = 0; t < 32; t++) {
        if (t < 31) STAGE((t + 1) * 64, cur ^ 1);

        // S^T = K Q^T : two 32x32 k-tiles, 4 K-steps of 16 over d
        f16v sf[2] = {};
        __builtin_amdgcn_s_setprio(1);
#pragma unroll
        for (int kt = 0; kt < 2; kt++) {
            int r = kt * 32 + l5;
            int swz = (r & 7) << 4;
#pragma unroll
            for (int st = 0; st < 4; st++) {
                s8v kf = *(const s8v*)((const char*)Ks[cur] + r * 128 + ((st * 32 + H * 16) ^ swz));
                sf[kt] = MFMA32(kf, qf[st], sf[kt]);
            }
        }
        __builtin_amdgcn_s_setprio(0);

        // row max (tree over 32 lane-local values, then pair-exchange)
        float mx[16];
#pragma unroll
        for (int i = 0; i < 16; i++) mx[i] = fmaxf(sf[0][i], sf[1][i]);
#pragma unroll
        for (int stp = 8; stp >= 1; stp >>= 1)
#pragma unroll
            for (int i = 0; i < stp; i++) mx[i] = fmaxf(mx[i], mx[i + stp]);
        float tm = fmaxf(mx[0], __shfl_xor(mx[0], 32, 64));

        // defer-max: skip rescale unless max grew past threshold (T13, THR=8)
        if (!__all(tm - m_ <= 8.0f)) {
            float mn = fmaxf(m_, tm);
            float fac = __builtin_amdgcn_exp2f(m_ - mn);
            m_ = mn;
            l_ *= fac;
#pragma unroll
            for (int dt = 0; dt < 2; dt++)
#pragma unroll
                for (int i = 0; i < 16; i++) oacc[dt][i] *= fac;
        }

        // P = exp2(S - m) in place; row-sum
        float rs0 = 0.f, rs1 = 0.f;
#pragma unroll
        for (int kt = 0; kt < 2; kt++)
#pragma unroll
            for (int i = 0; i < 16; i++) {
                float p = __builtin_amdgcn_exp2f(sf[kt][i] - m_);
                sf[kt][i] = p;
                if (i & 1) rs1 += p; else rs0 += p;
            }
        float rs = rs0 + rs1;
        rs += __shfl_xor(rs, 32, 64);
        l_ += rs;

        // O^T += V^T P^T : per 16-k step build P^T frag in-register, 2 mfma
#pragma unroll
        for (int s = 0; s < 4; s++) {
            const int kt = s >> 1, base = (s & 1) * 8;
            unsigned dA0 = cvt_pk_bf16(sf[kt][base + 0], sf[kt][base + 1]);
            unsigned dA1 = cvt_pk_bf16(sf[kt][base + 2], sf[kt][base + 3]);
            unsigned dB0 = cvt_pk_bf16(sf[kt][base + 4], sf[kt][base + 5]);
            unsigned dB1 = cvt_pk_bf16(sf[kt][base + 6], sf[kt][base + 7]);
            asm("v_permlane32_swap_b32 %0, %1" : "+v"(dA0), "+v"(dB0));
            asm("v_permlane32_swap_b32 %0, %1" : "+v"(dA1), "+v"(dB1));
            u4v fw = {dA0, dA1, dB0, dB1};
            s8v pfrag = __builtin_bit_cast(s8v, fw);
            __builtin_amdgcn_s_setprio(1);
#pragma unroll
            for (int dt = 0; dt < 2; dt++) {
                int r = dt * 32 + l5;
                s8v vf = *(const s8v*)((const char*)Vs[cur] + r * 128 + ((s * 32 + H * 16) ^ ((r & 7) << 4)));
                oacc[dt] = MFMA32(vf, pfrag, oacc[dt]);
            }
            __builtin_amdgcn_s_setprio(0);
        }
        __syncthreads();   // drains prefetch (vmcnt) + guards buffer swap
        cur ^= 1;
    }

    // normalize and store bf16 (O^T: q = l5 lane-local, d = dt*32 + 8g + 4H + j)
    float rl = 1.0f / l_;
    size_t orow = (size_t)(b * 2048 + q0 + l5) * 1024 + h * 64;
#pragma unroll
    for (int dt = 0; dt < 2; dt++)
#pragma unroll
        for (int g = 0; g < 4; g++) {
            short4 o;
            o.x = f2bf(oacc[dt][4 * g + 0] * rl);
            o.y = f2bf(oacc[dt][4 * g + 1] * rl);
            o.z = f2bf(oacc[dt][4 * g + 2] * rl);
            o.w = f2bf(oacc[dt][4 * g + 3] * rl);
            *(short4*)(AOb + orow + dt * 32 + g * 8 + H * 4) = o;
        }
}

// ---------------------------------------------------------------------------
extern "C" void kernel_launch(void* const* d_in, const int* in_sizes, int n_in,
                              void* d_out, int out_size, void* d_ws, size_t ws_size,
                              hipStream_t stream) {
    const float* x  = (const float*)d_in[0];
    const float* wq = (const float*)d_in[1];
    const float* bq = (const float*)d_in[2];
    const float* wk = (const float*)d_in[3];
    const float* bk = (const float*)d_in[4];
    const float* wv = (const float*)d_in[5];
    const float* bv = (const float*)d_in[6];
    const float* wo = (const float*)d_in[7];
    const float* bo = (const float*)d_in[8];
    float* out = (float*)d_out;

    char* ws = (char*)d_ws;
    const size_t MB16 = 16777216;  // 8192*1024*2
    short* xb  = (short*)(ws);              // x bf16 [8192][1024]
    short* qb  = (short*)(ws + 1 * MB16);   // Q bf16 (pre-scaled)
    short* kb  = (short*)(ws + 2 * MB16);   // K bf16
    short* vtb = (short*)(ws + 3 * MB16);   // V transposed bf16
    short* wT  = (short*)(ws + 4 * MB16);   // 4 x WT bf16 (wq,wk,wv,wo)
    short* aob = xb;                        // attention output reuses xb

    const float qscale = 0.125f * 1.4426950408889634f;  // 1/sqrt(64) * log2(e)

    convert_x<<<dim3(1024), dim3(256), 0, stream>>>((const float4*)x, (short4*)xb, 8388608 / 4);
    transpose_w<<<dim3(32, 32, 4), dim3(256), 0, stream>>>(wq, wk, wv, wo, wT);

    gemm_bt<short, 0><<<dim3(8, 64), dim3(256), 0, stream>>>(xb, wT, bq, qb, 8192, 1024, 1024, qscale);
    gemm_bt<short, 0><<<dim3(8, 64), dim3(256), 0, stream>>>(xb, wT + 1048576, bk, kb, 8192, 1024, 1024, 1.0f);
    gemm_bt<short, 1><<<dim3(64, 8), dim3(256), 0, stream>>>(wT + 2 * 1048576, xb, bv, vtb, 1024, 8192, 1024, 1.0f);

    attn_fwd<<<dim3(16, 64), dim3(256), 0, stream>>>(qb, kb, vtb, aob);

    gemm_bt<float, 0><<<dim3(8, 64), dim3(256), 0, stream>>>(aob, wT + 3 * 1048576, bo, out, 8192, 1024, 1024, 1.0f);
}